// Round 1
// baseline (48.249 us; speedup 1.0000x reference)
//
#include <hip/hip_runtime.h>

// Problem constants
#define NN 20000
#define SS 400
#define QQ 20
#define PP 3
#define QP (QQ*PP)        // 60 floats per row
#define SROW 64           // padded row stride for heads2 in ws (256B aligned rows)
#define SPLIT 8           // s-split factor = waves per block
#define SCHUNK (SS/SPLIT) // 50 s-values per wave
#define BLK_B 512         // 8 waves
#define NPB 64            // n per block (one per lane)
#define NBLK ((NN + NPB - 1)/NPB)  // 313

// ws layout (floats):
#define WS_HEADS 0
#define WS_RATIOS (SS*SROW)            // 25600
#define WS_PART   (WS_RATIOS + SS)     // 26000

__global__ void prep_kernel(const float* __restrict__ heads_param,
                            const float* __restrict__ ratios_param,
                            float* __restrict__ out, float* __restrict__ ws) {
    int i = blockIdx.x * blockDim.x + threadIdx.x;
    if (i < SS*QP) {
        float v = heads_param[i];
        float v2 = v * v;
        out[1 + SS + i] = v2;              // heads output section
        int s = i / QP;
        int r = i - s * QP;
        ws[WS_HEADS + s*SROW + r] = v2;    // padded table for main kernel
    }
    if (i < SS) {
        float v = ratios_param[i];
        float v2 = v * v;
        out[1 + i] = v2;                   // ratios output section
        ws[WS_RATIOS + i] = v2;
    }
}

__global__ __launch_bounds__(BLK_B) void main_kernel(
        const float* __restrict__ pauli, const float* __restrict__ coeff,
        float* __restrict__ ws) {
    __shared__ float lds_cov[SPLIT][NPB];

    const int tid  = threadIdx.x;
    const int wave = __builtin_amdgcn_readfirstlane(tid >> 6);
    const int lane = tid & 63;
    const int n = blockIdx.x * NPB + lane;
    const bool valid = (n < NN);
    const int nc = valid ? n : (NN - 1);

    // Load this lane's pauli row: 60 floats via 15 x float4 (240B, 16B aligned)
    float pl[QP];
    const float4* p4 = reinterpret_cast<const float4*>(pauli + (size_t)nc * QP);
    #pragma unroll
    for (int i = 0; i < QP/4; ++i) {
        float4 v = p4[i];
        pl[i*4+0] = v.x; pl[i*4+1] = v.y; pl[i*4+2] = v.z; pl[i*4+3] = v.w;
    }

    const float* __restrict__ h2 = ws + WS_HEADS;
    const float* __restrict__ r2 = ws + WS_RATIOS;

    float cov = 0.f;
    const int s0 = wave * SCHUNK;
    for (int si = 0; si < SCHUNK; ++si) {
        const int s = s0 + si;
        const float* __restrict__ hrow = h2 + s * SROW;  // wave-uniform address
        float pr0 = 1.f, pr1 = 1.f, pr2 = 1.f, pr3 = 1.f;
        #pragma unroll
        for (int q = 0; q < QQ; q += 4) {
            float d0 = hrow[(q+0)*3+0]*pl[(q+0)*3+0] + hrow[(q+0)*3+1]*pl[(q+0)*3+1] + hrow[(q+0)*3+2]*pl[(q+0)*3+2];
            float d1 = hrow[(q+1)*3+0]*pl[(q+1)*3+0] + hrow[(q+1)*3+1]*pl[(q+1)*3+1] + hrow[(q+1)*3+2]*pl[(q+1)*3+2];
            float d2 = hrow[(q+2)*3+0]*pl[(q+2)*3+0] + hrow[(q+2)*3+1]*pl[(q+2)*3+1] + hrow[(q+2)*3+2]*pl[(q+2)*3+2];
            float d3 = hrow[(q+3)*3+0]*pl[(q+3)*3+0] + hrow[(q+3)*3+1]*pl[(q+3)*3+1] + hrow[(q+3)*3+2]*pl[(q+3)*3+2];
            pr0 *= d0; pr1 *= d1; pr2 *= d2; pr3 *= d3;
        }
        cov += r2[s] * ((pr0*pr1) * (pr2*pr3));
    }

    lds_cov[wave][lane] = cov;
    __syncthreads();

    if (tid < NPB) {
        float c = 0.f;
        #pragma unroll
        for (int w = 0; w < SPLIT; ++w) c += lds_cov[w][tid];
        // n for tid<64 equals blockIdx*NPB+tid (lane==tid)
        float cf = valid ? coeff[n] : 0.f;
        float term = valid ? (cf * cf) / c : 0.f;
        #pragma unroll
        for (int off = 32; off; off >>= 1) term += __shfl_down(term, off);
        if (tid == 0) ws[WS_PART + blockIdx.x] = term;
    }
}

__global__ void final_kernel(const float* __restrict__ ws, float* __restrict__ out) {
    int tid = threadIdx.x;  // 64 threads
    double acc = 0.0;
    for (int i = tid; i < NBLK; i += 64) acc += (double)ws[WS_PART + i];
    #pragma unroll
    for (int off = 32; off; off >>= 1) acc += __shfl_down(acc, off);
    if (tid == 0) out[0] = (float)acc;
}

extern "C" void kernel_launch(void* const* d_in, const int* in_sizes, int n_in,
                              void* d_out, int out_size, void* d_ws, size_t ws_size,
                              hipStream_t stream) {
    const float* heads_param  = (const float*)d_in[0];   // [S,Q,P]
    const float* ratios_param = (const float*)d_in[1];   // [S]
    const float* pauli        = (const float*)d_in[2];   // [N,Q,P]
    const float* coeff        = (const float*)d_in[3];   // [N]
    float* out = (float*)d_out;
    float* ws  = (float*)d_ws;

    prep_kernel<<<(SS*QP + 255)/256, 256, 0, stream>>>(heads_param, ratios_param, out, ws);
    main_kernel<<<NBLK, BLK_B, 0, stream>>>(pauli, coeff, ws);
    final_kernel<<<1, 64, 0, stream>>>(ws, out);
}